// Round 13
// baseline (599.956 us; speedup 1.0000x reference)
//
#include <hip/hip_runtime.h>

#define NPTS   1048576
#define NLEV   16
#define TSIZE  (1u << 19)
#define HMASK  (TSIZE - 1u)
#define NBUCK  32768          // 32^3 Morton buckets
#define FINE_GRID 2048        // persistent blocks for fines (8/CU at VGPR~20)

// floor(16 * b^l), b = 32^(1/15): f32-correct values
__device__ __constant__ float NLF_TAB[16] = {
    16.f, 20.f, 25.f, 32.f, 40.f, 50.f, 64.f, 80.f,
    101.f, 128.f, 161.f, 203.f, 256.f, 322.f, 406.f, 512.f};

__device__ __forceinline__ unsigned spread5(unsigned x) {
    x &= 0x1F;
    x = (x | (x << 8)) & 0x100F;
    x = (x | (x << 4)) & 0x10C3;
    x = (x | (x << 2)) & 0x1249;
    return x;
}

__device__ __forceinline__ unsigned morton_key(float u0, float u1, float u2) {
    unsigned k0 = min(31u, (unsigned)(u0 * 32.0f));
    unsigned k1 = min(31u, (unsigned)(u1 * 32.0f));
    unsigned k2 = min(31u, (unsigned)(u2 * 32.0f));
    return (spread5(k0) << 2) | (spread5(k1) << 1) | spread5(k2);
}

__device__ __forceinline__ void uvw(float x0, float x1, float x2,
                                    float* u0, float* u1, float* u2) {
    const float mn = -1.5f, mx = 1.5f, rng = 3.0f;
    *u0 = (fminf(fmaxf(x0, mn), mx) - mn) / rng;
    *u1 = (fminf(fmaxf(x1, mn), mx) - mn) / rng;
    *u2 = (fminf(fmaxf(x2, mn), mx) - mn) / rng;
}

__device__ __forceinline__ void level_lerp(
    float x0, float x1, float x2, float u0, float u1, float u2,
    float Nl, const float2* __restrict__ tab, float* r0, float* r1)
{
#pragma clang fp contract(off)
    const float mn = -1.5f, rng = 3.0f;
    const float box = rng / Nl;

    int g0 = (int)floorf(u0 * Nl);
    int g1 = (int)floorf(u1 * Nl);
    int g2 = (int)floorf(u2 * Nl);

    float vmin0 = (float)g0 * box + mn;
    float vmin1 = (float)g1 * box + mn;
    float vmin2 = (float)g2 * box + mn;

    float den0 = (vmin0 + box) - vmin0;
    float den1 = (vmin1 + box) - vmin1;
    float den2 = (vmin2 + box) - vmin2;

    float wx = (x0 - vmin0) / den0;
    float wy = (x1 - vmin1) / den1;
    float wz = (x2 - vmin2) / den2;

    unsigned hx0 = (unsigned)g0;
    unsigned hx1 = (unsigned)(g0 + 1);
    unsigned hy0 = (unsigned)g1       * 2654435761u;
    unsigned hy1 = (unsigned)(g1 + 1) * 2654435761u;
    unsigned hz0 = (unsigned)g2       * 805459861u;
    unsigned hz1 = (unsigned)(g2 + 1) * 805459861u;

    float2 e000 = tab[(hx0 ^ hy0 ^ hz0) & HMASK];
    float2 e001 = tab[(hx0 ^ hy0 ^ hz1) & HMASK];
    float2 e010 = tab[(hx0 ^ hy1 ^ hz0) & HMASK];
    float2 e011 = tab[(hx0 ^ hy1 ^ hz1) & HMASK];
    float2 e100 = tab[(hx1 ^ hy0 ^ hz0) & HMASK];
    float2 e101 = tab[(hx1 ^ hy0 ^ hz1) & HMASK];
    float2 e110 = tab[(hx1 ^ hy1 ^ hz0) & HMASK];
    float2 e111 = tab[(hx1 ^ hy1 ^ hz1) & HMASK];

    float omx = 1.0f - wx, omy = 1.0f - wy, omz = 1.0f - wz;
    {
        float c00 = e000.x * omx + e100.x * wx;
        float c01 = e001.x * omx + e101.x * wx;
        float c10 = e010.x * omx + e110.x * wx;
        float c11 = e011.x * omx + e111.x * wx;
        float c0  = c00 * omy + c10 * wy;
        float c1  = c01 * omy + c11 * wy;
        *r0 = c0 * omz + c1 * wz;
    }
    {
        float c00 = e000.y * omx + e100.y * wx;
        float c01 = e001.y * omx + e101.y * wx;
        float c10 = e010.y * omx + e110.y * wx;
        float c11 = e011.y * omx + e111.y * wx;
        float c0  = c00 * omy + c10 * wy;
        float c1  = c01 * omy + c11 * wy;
        *r1 = c0 * omz + c1 * wz;
    }
}

// ---------- sort kernels ----------

__global__ __launch_bounds__(1024)
void scan_kernel(unsigned* __restrict__ hist, unsigned* __restrict__ cursor)
{
    __shared__ unsigned part[1024];
    int t = threadIdx.x;
    unsigned local[32];
    unsigned s = 0;
#pragma unroll
    for (int i = 0; i < 32; ++i) { local[i] = hist[t * 32 + i]; s += local[i]; }
    part[t] = s;
    __syncthreads();
    for (int off = 1; off < 1024; off <<= 1) {
        unsigned v = (t >= off) ? part[t - off] : 0;
        __syncthreads();
        part[t] += v;
        __syncthreads();
    }
    unsigned base = (t == 0) ? 0u : part[t - 1];
#pragma unroll
    for (int i = 0; i < 32; ++i) {
        cursor[t * 32 + i] = base;
        base += local[i];
    }
}

__global__ __launch_bounds__(256)
void scatter_kernel(const float* __restrict__ xin,
                    unsigned* __restrict__ cursor,
                    unsigned* __restrict__ sidx,
                    float4* __restrict__ sx4)
{
    int p = blockIdx.x * 256 + threadIdx.x;
    if (p >= NPTS) return;
    float x0 = xin[3 * p], x1 = xin[3 * p + 1], x2 = xin[3 * p + 2];
    float u0, u1, u2; uvw(x0, x1, x2, &u0, &u1, &u2);
    unsigned pos = atomicAdd(&cursor[morton_key(u0, u1, u2)], 1u);
    sidx[pos] = (unsigned)p;
    sx4[pos] = make_float4(x0, x1, x2, 0.0f);
}

// ---------- compute kernels ----------

// Levels 0..7 over sorted points; writes first 64B of each row (full line).
__global__ __launch_bounds__(256)
void coarse_sorted(const unsigned* __restrict__ sidx,
                   const float4* __restrict__ sx4,
                   const float* __restrict__ tables,
                   float* __restrict__ out)
{
#pragma clang fp contract(off)
    int s = blockIdx.x * 256 + threadIdx.x;
    if (s >= NPTS) return;
    unsigned p = sidx[s];
    float4 xv = sx4[s];
    float u0, u1, u2; uvw(xv.x, xv.y, xv.z, &u0, &u1, &u2);

    float res[16];
#pragma unroll
    for (int l = 0; l < 8; ++l) {
        const float2* tab = (const float2*)tables + (size_t)l * TSIZE;
        level_lerp(xv.x, xv.y, xv.z, u0, u1, u2, NLF_TAB[l], tab,
                   &res[2 * l], &res[2 * l + 1]);
    }

    float4* orow = (float4*)(out + (size_t)p * 32);
#pragma unroll
    for (int i = 0; i < 4; ++i)
        orow[i] = make_float4(res[4 * i + 0], res[4 * i + 1],
                              res[4 * i + 2], res[4 * i + 3]);
}

// Levels 8,9 over sorted points; writes one float4 (floats 16..19).
__global__ __launch_bounds__(256)
void mid_sorted(const unsigned* __restrict__ sidx,
                const float4* __restrict__ sx4,
                const float* __restrict__ tables,
                float* __restrict__ out)
{
#pragma clang fp contract(off)
    int s = blockIdx.x * 256 + threadIdx.x;
    if (s >= NPTS) return;
    unsigned p = sidx[s];
    float4 xv = sx4[s];
    float u0, u1, u2; uvw(xv.x, xv.y, xv.z, &u0, &u1, &u2);

    float r[4];
    {
        const float2* tab = (const float2*)tables + (size_t)8 * TSIZE;
        level_lerp(xv.x, xv.y, xv.z, u0, u1, u2, NLF_TAB[8], tab, &r[0], &r[1]);
    }
    {
        const float2* tab = (const float2*)tables + (size_t)9 * TSIZE;
        level_lerp(xv.x, xv.y, xv.z, u0, u1, u2, NLF_TAB[9], tab, &r[2], &r[3]);
    }
    *(float4*)(out + (size_t)p * 32 + 16) = make_float4(r[0], r[1], r[2], r[3]);
}

// All six fine levels (10..15) in ONE persistent dispatch. FINE_GRID blocks
// grid-stride in order through 6*4096 virtual blocks: every resident block
// works on ~the same level at ~the same time -> one 4MB table L2-resident,
// without per-level launch gaps.
template<bool DO_HIST>
__global__ __launch_bounds__(256)
void fines_persist(const float* __restrict__ xin,
                   const float* __restrict__ tables,
                   float* __restrict__ out,
                   unsigned* __restrict__ hist)
{
#pragma clang fp contract(off)
    for (int vb = blockIdx.x; vb < 6 * 4096; vb += FINE_GRID) {
        int lev = 15 - (vb >> 12);                       // 4096 vblocks/level
        int p   = (vb & 4095) * 256 + (int)threadIdx.x;  // < NPTS exactly

        float x0 = xin[3 * p], x1 = xin[3 * p + 1], x2 = xin[3 * p + 2];
        float u0, u1, u2; uvw(x0, x1, x2, &u0, &u1, &u2);

        if (DO_HIST && lev == 15)
            atomicAdd(&hist[morton_key(u0, u1, u2)], 1u);

        const float2* tab = (const float2*)tables + (size_t)lev * TSIZE;
        float r0, r1;
        level_lerp(x0, x1, x2, u0, u1, u2, NLF_TAB[lev], tab, &r0, &r1);
        *(float2*)(out + (size_t)p * 32 + 2 * lev) = make_float2(r0, r1);

        if (lev == 10) {
            const float mn = -1.5f, mx = 1.5f;
            float keep = (x0 >= mn && x0 <= mx &&
                          x1 >= mn && x1 <= mx &&
                          x2 >= mn && x2 <= mx) ? 1.0f : 0.0f;
            out[(size_t)NPTS * 32 + p] = keep;
        }
    }
}

// ---------- fallback (no-workspace path) ----------

__global__ __launch_bounds__(256)
void coarse_kernel(const float* __restrict__ xin,
                   const float* __restrict__ tables,
                   float* __restrict__ out)
{
#pragma clang fp contract(off)
    int p = blockIdx.x * 256 + threadIdx.x;
    if (p >= NPTS) return;
    float x0 = xin[3 * p], x1 = xin[3 * p + 1], x2 = xin[3 * p + 2];
    float u0, u1, u2; uvw(x0, x1, x2, &u0, &u1, &u2);

    float res[16];
#pragma unroll
    for (int l = 0; l < 8; ++l) {
        const float2* tab = (const float2*)tables + (size_t)l * TSIZE;
        level_lerp(x0, x1, x2, u0, u1, u2, NLF_TAB[l], tab,
                   &res[2 * l], &res[2 * l + 1]);
    }
    float4* orow = (float4*)(out + (size_t)p * 32);
#pragma unroll
    for (int i = 0; i < 4; ++i)
        orow[i] = make_float4(res[4 * i + 0], res[4 * i + 1],
                              res[4 * i + 2], res[4 * i + 3]);
}

template<int L>
__global__ __launch_bounds__(256)
void fine_plain(const float* __restrict__ xin,
                const float* __restrict__ tables,
                float* __restrict__ out)
{
#pragma clang fp contract(off)
    int p = blockIdx.x * 256 + threadIdx.x;
    if (p >= NPTS) return;
    float x0 = xin[3 * p], x1 = xin[3 * p + 1], x2 = xin[3 * p + 2];
    float u0, u1, u2; uvw(x0, x1, x2, &u0, &u1, &u2);

    const float2* tab = (const float2*)tables + (size_t)L * TSIZE;
    float r0, r1;
    level_lerp(x0, x1, x2, u0, u1, u2, NLF_TAB[L], tab, &r0, &r1);
    *(float2*)(out + (size_t)p * 32 + 2 * L) = make_float2(r0, r1);
}

extern "C" void kernel_launch(void* const* d_in, const int* in_sizes, int n_in,
                              void* d_out, int out_size, void* d_ws, size_t ws_size,
                              hipStream_t stream) {
    const float* x      = (const float*)d_in[0];
    const float* tables = (const float*)d_in[2];
    float* out = (float*)d_out;

    int n = in_sizes[0] / 3;           // 1048576
    int blocks = (n + 255) / 256;      // 4096

    const size_t HIST_B   = (size_t)NBUCK * 4;              // 128 KB
    const size_t SIDX_OFF = 131072;                         // aligned
    const size_t SX4_OFF  = SIDX_OFF + (size_t)NPTS * 4;    // +4 MB
    const size_t NEEDED   = SX4_OFF + (size_t)NPTS * 16;    // ≈ 20.2 MB

    if (ws_size >= NEEDED) {
        unsigned* hist = (unsigned*)d_ws;
        unsigned* sidx = (unsigned*)((char*)d_ws + SIDX_OFF);
        float4*   sx4  = (float4*)((char*)d_ws + SX4_OFF);

        hipMemsetAsync(hist, 0, HIST_B, stream);

        // Persistent fines sweep levels 15..10 in phase; L15 builds hist.
        fines_persist<true><<<FINE_GRID, 256, 0, stream>>>(x, tables, out, hist);

        scan_kernel<<<1, 1024, 0, stream>>>(hist, hist);  // in-place -> cursors
        scatter_kernel<<<blocks, 256, 0, stream>>>(x, hist, sidx, sx4);
        coarse_sorted<<<blocks, 256, 0, stream>>>(sidx, sx4, tables, out);
        mid_sorted<<<blocks, 256, 0, stream>>>(sidx, sx4, tables, out);
    } else {
        coarse_kernel<<<blocks, 256, 0, stream>>>(x, tables, out);
        fine_plain< 8><<<blocks, 256, 0, stream>>>(x, tables, out);
        fine_plain< 9><<<blocks, 256, 0, stream>>>(x, tables, out);
        fines_persist<false><<<FINE_GRID, 256, 0, stream>>>(x, tables, out, nullptr);
    }
}

// Round 14
// 455.822 us; speedup vs baseline: 1.3162x; 1.3162x over previous
//
#include <hip/hip_runtime.h>

#define NPTS   1048576
#define NLEV   16
#define TSIZE  (1u << 19)
#define HMASK  (TSIZE - 1u)
#define NBUCK  32768          // 32^3 Morton buckets

// floor(16 * b^l), b = 32^(1/15): f32-correct values
__device__ __constant__ float NLF_TAB[16] = {
    16.f, 20.f, 25.f, 32.f, 40.f, 50.f, 64.f, 80.f,
    101.f, 128.f, 161.f, 203.f, 256.f, 322.f, 406.f, 512.f};

__device__ __forceinline__ unsigned spread5(unsigned x) {
    x &= 0x1F;
    x = (x | (x << 8)) & 0x100F;
    x = (x | (x << 4)) & 0x10C3;
    x = (x | (x << 2)) & 0x1249;
    return x;
}

__device__ __forceinline__ unsigned morton_key(float u0, float u1, float u2) {
    unsigned k0 = min(31u, (unsigned)(u0 * 32.0f));
    unsigned k1 = min(31u, (unsigned)(u1 * 32.0f));
    unsigned k2 = min(31u, (unsigned)(u2 * 32.0f));
    return (spread5(k0) << 2) | (spread5(k1) << 1) | spread5(k2);
}

__device__ __forceinline__ void uvw(float x0, float x1, float x2,
                                    float* u0, float* u1, float* u2) {
    const float mn = -1.5f, mx = 1.5f, rng = 3.0f;
    *u0 = (fminf(fmaxf(x0, mn), mx) - mn) / rng;
    *u1 = (fminf(fmaxf(x1, mn), mx) - mn) / rng;
    *u2 = (fminf(fmaxf(x2, mn), mx) - mn) / rng;
}

__device__ __forceinline__ void level_lerp(
    float x0, float x1, float x2, float u0, float u1, float u2,
    float Nl, const float2* __restrict__ tab, float* r0, float* r1)
{
#pragma clang fp contract(off)
    const float mn = -1.5f, rng = 3.0f;
    const float box = rng / Nl;

    int g0 = (int)floorf(u0 * Nl);
    int g1 = (int)floorf(u1 * Nl);
    int g2 = (int)floorf(u2 * Nl);

    float vmin0 = (float)g0 * box + mn;
    float vmin1 = (float)g1 * box + mn;
    float vmin2 = (float)g2 * box + mn;

    float den0 = (vmin0 + box) - vmin0;
    float den1 = (vmin1 + box) - vmin1;
    float den2 = (vmin2 + box) - vmin2;

    float wx = (x0 - vmin0) / den0;
    float wy = (x1 - vmin1) / den1;
    float wz = (x2 - vmin2) / den2;

    unsigned hx0 = (unsigned)g0;
    unsigned hx1 = (unsigned)(g0 + 1);
    unsigned hy0 = (unsigned)g1       * 2654435761u;
    unsigned hy1 = (unsigned)(g1 + 1) * 2654435761u;
    unsigned hz0 = (unsigned)g2       * 805459861u;
    unsigned hz1 = (unsigned)(g2 + 1) * 805459861u;

    float2 e000 = tab[(hx0 ^ hy0 ^ hz0) & HMASK];
    float2 e001 = tab[(hx0 ^ hy0 ^ hz1) & HMASK];
    float2 e010 = tab[(hx0 ^ hy1 ^ hz0) & HMASK];
    float2 e011 = tab[(hx0 ^ hy1 ^ hz1) & HMASK];
    float2 e100 = tab[(hx1 ^ hy0 ^ hz0) & HMASK];
    float2 e101 = tab[(hx1 ^ hy0 ^ hz1) & HMASK];
    float2 e110 = tab[(hx1 ^ hy1 ^ hz0) & HMASK];
    float2 e111 = tab[(hx1 ^ hy1 ^ hz1) & HMASK];

    float omx = 1.0f - wx, omy = 1.0f - wy, omz = 1.0f - wz;
    {
        float c00 = e000.x * omx + e100.x * wx;
        float c01 = e001.x * omx + e101.x * wx;
        float c10 = e010.x * omx + e110.x * wx;
        float c11 = e011.x * omx + e111.x * wx;
        float c0  = c00 * omy + c10 * wy;
        float c1  = c01 * omy + c11 * wy;
        *r0 = c0 * omz + c1 * wz;
    }
    {
        float c00 = e000.y * omx + e100.y * wx;
        float c01 = e001.y * omx + e101.y * wx;
        float c10 = e010.y * omx + e110.y * wx;
        float c11 = e011.y * omx + e111.y * wx;
        float c0  = c00 * omy + c10 * wy;
        float c1  = c01 * omy + c11 * wy;
        *r1 = c0 * omz + c1 * wz;
    }
}

// ---------- fine-level body ----------

template<int L, bool DO_HIST, bool DO_MASK>
__device__ __forceinline__ void fine_body(
    const float* __restrict__ xin, const float* __restrict__ tables,
    float* __restrict__ out, unsigned* __restrict__ hist, int p)
{
#pragma clang fp contract(off)
    float x0 = xin[3 * p], x1 = xin[3 * p + 1], x2 = xin[3 * p + 2];
    float u0, u1, u2; uvw(x0, x1, x2, &u0, &u1, &u2);

    if (DO_HIST)
        atomicAdd(&hist[morton_key(u0, u1, u2)], 1u);

    const float2* tab = (const float2*)tables + (size_t)L * TSIZE;
    float r0, r1;
    level_lerp(x0, x1, x2, u0, u1, u2, NLF_TAB[L], tab, &r0, &r1);
    *(float2*)(out + (size_t)p * 32 + 2 * L) = make_float2(r0, r1);

    if (DO_MASK) {
        const float mn = -1.5f, mx = 1.5f;
        float keep = (x0 >= mn && x0 <= mx &&
                      x1 >= mn && x1 <= mx &&
                      x2 >= mn && x2 <= mx) ? 1.0f : 0.0f;
        out[(size_t)NPTS * 32 + p] = keep;
    }
}

template<int L, bool DO_HIST, bool DO_MASK>
__global__ __launch_bounds__(256)
void fine_kernel(const float* __restrict__ xin,
                 const float* __restrict__ tables,
                 float* __restrict__ out,
                 unsigned* __restrict__ hist)
{
    int p = blockIdx.x * 256 + threadIdx.x;
    if (p >= NPTS) return;
    fine_body<L, DO_HIST, DO_MASK>(xin, tables, out, hist, p);
}

// fine14 + scan: blocks 0..4095 do L14; block 4096 scans the (complete)
// histogram into cursors in-place. Runs concurrently with the gathers.
__global__ __launch_bounds__(256)
void fine14_scan(const float* __restrict__ xin,
                 const float* __restrict__ tables,
                 float* __restrict__ out,
                 unsigned* __restrict__ hist)
{
    __shared__ unsigned part[256];
    if (blockIdx.x < 4096) {
        int p = blockIdx.x * 256 + threadIdx.x;
        fine_body<14, false, false>(xin, tables, out, hist, p);
        return;
    }
    // --- scan block: 256 threads x 128 bins ---
    int t = threadIdx.x;
    unsigned s = 0;
    for (int i = 0; i < 128; ++i) s += hist[t * 128 + i];
    part[t] = s;
    __syncthreads();
    for (int off = 1; off < 256; off <<= 1) {
        unsigned v = (t >= off) ? part[t - off] : 0;
        __syncthreads();
        part[t] += v;
        __syncthreads();
    }
    unsigned base = (t == 0) ? 0u : part[t - 1];
    for (int i = 0; i < 128; ++i) {
        unsigned c = hist[t * 128 + i];
        hist[t * 128 + i] = base;     // cursor
        base += c;
    }
}

// fine13 + scatter: blocks 0..4095 do L13; blocks 4096..8191 scatter points
// into sorted order using the (complete) cursors.
__global__ __launch_bounds__(256)
void fine13_scatter(const float* __restrict__ xin,
                    const float* __restrict__ tables,
                    float* __restrict__ out,
                    unsigned* __restrict__ cursor,
                    unsigned* __restrict__ sidx,
                    float4* __restrict__ sx4)
{
    if (blockIdx.x < 4096) {
        int p = blockIdx.x * 256 + threadIdx.x;
        fine_body<13, false, false>(xin, tables, out, (unsigned*)nullptr, p);
        return;
    }
    int p = (blockIdx.x - 4096) * 256 + threadIdx.x;
    float x0 = xin[3 * p], x1 = xin[3 * p + 1], x2 = xin[3 * p + 2];
    float u0, u1, u2; uvw(x0, x1, x2, &u0, &u1, &u2);
    unsigned pos = atomicAdd(&cursor[morton_key(u0, u1, u2)], 1u);
    sidx[pos] = (unsigned)p;
    sx4[pos] = make_float4(x0, x1, x2, 0.0f);
}

// ---------- sorted compute kernels ----------

// Levels 0..7 over sorted points; writes first 64B of each row (full line).
__global__ __launch_bounds__(256)
void coarse_sorted(const unsigned* __restrict__ sidx,
                   const float4* __restrict__ sx4,
                   const float* __restrict__ tables,
                   float* __restrict__ out)
{
#pragma clang fp contract(off)
    int s = blockIdx.x * 256 + threadIdx.x;
    if (s >= NPTS) return;
    unsigned p = sidx[s];
    float4 xv = sx4[s];
    float u0, u1, u2; uvw(xv.x, xv.y, xv.z, &u0, &u1, &u2);

    float res[16];
#pragma unroll
    for (int l = 0; l < 8; ++l) {
        const float2* tab = (const float2*)tables + (size_t)l * TSIZE;
        level_lerp(xv.x, xv.y, xv.z, u0, u1, u2, NLF_TAB[l], tab,
                   &res[2 * l], &res[2 * l + 1]);
    }

    float4* orow = (float4*)(out + (size_t)p * 32);
#pragma unroll
    for (int i = 0; i < 4; ++i)
        orow[i] = make_float4(res[4 * i + 0], res[4 * i + 1],
                              res[4 * i + 2], res[4 * i + 3]);
}

// Levels 8,9 over sorted points; writes one float4 (floats 16..19).
__global__ __launch_bounds__(256)
void mid_sorted(const unsigned* __restrict__ sidx,
                const float4* __restrict__ sx4,
                const float* __restrict__ tables,
                float* __restrict__ out)
{
#pragma clang fp contract(off)
    int s = blockIdx.x * 256 + threadIdx.x;
    if (s >= NPTS) return;
    unsigned p = sidx[s];
    float4 xv = sx4[s];
    float u0, u1, u2; uvw(xv.x, xv.y, xv.z, &u0, &u1, &u2);

    float r[4];
    {
        const float2* tab = (const float2*)tables + (size_t)8 * TSIZE;
        level_lerp(xv.x, xv.y, xv.z, u0, u1, u2, NLF_TAB[8], tab, &r[0], &r[1]);
    }
    {
        const float2* tab = (const float2*)tables + (size_t)9 * TSIZE;
        level_lerp(xv.x, xv.y, xv.z, u0, u1, u2, NLF_TAB[9], tab, &r[2], &r[3]);
    }
    *(float4*)(out + (size_t)p * 32 + 16) = make_float4(r[0], r[1], r[2], r[3]);
}

// ---------- fallback (no-workspace path) ----------

__global__ __launch_bounds__(256)
void coarse_kernel(const float* __restrict__ xin,
                   const float* __restrict__ tables,
                   float* __restrict__ out)
{
#pragma clang fp contract(off)
    int p = blockIdx.x * 256 + threadIdx.x;
    if (p >= NPTS) return;
    float x0 = xin[3 * p], x1 = xin[3 * p + 1], x2 = xin[3 * p + 2];
    float u0, u1, u2; uvw(x0, x1, x2, &u0, &u1, &u2);

    float res[16];
#pragma unroll
    for (int l = 0; l < 8; ++l) {
        const float2* tab = (const float2*)tables + (size_t)l * TSIZE;
        level_lerp(x0, x1, x2, u0, u1, u2, NLF_TAB[l], tab,
                   &res[2 * l], &res[2 * l + 1]);
    }
    float4* orow = (float4*)(out + (size_t)p * 32);
#pragma unroll
    for (int i = 0; i < 4; ++i)
        orow[i] = make_float4(res[4 * i + 0], res[4 * i + 1],
                              res[4 * i + 2], res[4 * i + 3]);
}

extern "C" void kernel_launch(void* const* d_in, const int* in_sizes, int n_in,
                              void* d_out, int out_size, void* d_ws, size_t ws_size,
                              hipStream_t stream) {
    const float* x      = (const float*)d_in[0];
    const float* tables = (const float*)d_in[2];
    float* out = (float*)d_out;

    int n = in_sizes[0] / 3;           // 1048576
    int blocks = (n + 255) / 256;      // 4096

    const size_t HIST_B   = (size_t)NBUCK * 4;              // 128 KB
    const size_t SIDX_OFF = 131072;                         // aligned
    const size_t SX4_OFF  = SIDX_OFF + (size_t)NPTS * 4;    // +4 MB
    const size_t NEEDED   = SX4_OFF + (size_t)NPTS * 16;    // ≈ 20.2 MB

    if (ws_size >= NEEDED) {
        unsigned* hist = (unsigned*)d_ws;
        unsigned* sidx = (unsigned*)((char*)d_ws + SIDX_OFF);
        float4*   sx4  = (float4*)((char*)d_ws + SX4_OFF);

        hipMemsetAsync(hist, 0, HIST_B, stream);

        // One table L2-resident per launch; sort piggybacks on fine launches.
        fine_kernel<15, true , false><<<blocks, 256, 0, stream>>>(x, tables, out, hist);
        fine14_scan<<<blocks + 1, 256, 0, stream>>>(x, tables, out, hist);
        fine13_scatter<<<2 * blocks, 256, 0, stream>>>(x, tables, out, hist, sidx, sx4);
        fine_kernel<12, false, false><<<blocks, 256, 0, stream>>>(x, tables, out, hist);
        fine_kernel<11, false, false><<<blocks, 256, 0, stream>>>(x, tables, out, hist);
        fine_kernel<10, false, true ><<<blocks, 256, 0, stream>>>(x, tables, out, hist);

        coarse_sorted<<<blocks, 256, 0, stream>>>(sidx, sx4, tables, out);
        mid_sorted<<<blocks, 256, 0, stream>>>(sidx, sx4, tables, out);
    } else {
        coarse_kernel<<<blocks, 256, 0, stream>>>(x, tables, out);
        fine_kernel< 8, false, false><<<blocks, 256, 0, stream>>>(x, tables, out, nullptr);
        fine_kernel< 9, false, false><<<blocks, 256, 0, stream>>>(x, tables, out, nullptr);
        fine_kernel<10, false, true ><<<blocks, 256, 0, stream>>>(x, tables, out, nullptr);
        fine_kernel<11, false, false><<<blocks, 256, 0, stream>>>(x, tables, out, nullptr);
        fine_kernel<12, false, false><<<blocks, 256, 0, stream>>>(x, tables, out, nullptr);
        fine_kernel<13, false, false><<<blocks, 256, 0, stream>>>(x, tables, out, nullptr);
        fine_kernel<14, false, false><<<blocks, 256, 0, stream>>>(x, tables, out, nullptr);
        fine_kernel<15, false, false><<<blocks, 256, 0, stream>>>(x, tables, out, nullptr);
    }
}

// Round 15
// 448.684 us; speedup vs baseline: 1.3371x; 1.0159x over previous
//
#include <hip/hip_runtime.h>

#define NPTS   1048576
#define NLEV   16
#define TSIZE  (1u << 19)
#define HMASK  (TSIZE - 1u)
#define NBUCK  32768          // 32^3 Morton buckets

// floor(16 * b^l), b = 32^(1/15): f32-correct values
__device__ __constant__ float NLF_TAB[16] = {
    16.f, 20.f, 25.f, 32.f, 40.f, 50.f, 64.f, 80.f,
    101.f, 128.f, 161.f, 203.f, 256.f, 322.f, 406.f, 512.f};

__device__ __forceinline__ unsigned spread5(unsigned x) {
    x &= 0x1F;
    x = (x | (x << 8)) & 0x100F;
    x = (x | (x << 4)) & 0x10C3;
    x = (x | (x << 2)) & 0x1249;
    return x;
}

__device__ __forceinline__ unsigned morton_key(float u0, float u1, float u2) {
    unsigned k0 = min(31u, (unsigned)(u0 * 32.0f));
    unsigned k1 = min(31u, (unsigned)(u1 * 32.0f));
    unsigned k2 = min(31u, (unsigned)(u2 * 32.0f));
    return (spread5(k0) << 2) | (spread5(k1) << 1) | spread5(k2);
}

__device__ __forceinline__ void uvw(float x0, float x1, float x2,
                                    float* u0, float* u1, float* u2) {
    const float mn = -1.5f, mx = 1.5f, rng = 3.0f;
    *u0 = (fminf(fmaxf(x0, mn), mx) - mn) / rng;
    *u1 = (fminf(fmaxf(x1, mn), mx) - mn) / rng;
    *u2 = (fminf(fmaxf(x2, mn), mx) - mn) / rng;
}

__device__ __forceinline__ void level_lerp(
    float x0, float x1, float x2, float u0, float u1, float u2,
    float Nl, const float2* __restrict__ tab, float* r0, float* r1)
{
#pragma clang fp contract(off)
    const float mn = -1.5f, rng = 3.0f;
    const float box = rng / Nl;

    int g0 = (int)floorf(u0 * Nl);
    int g1 = (int)floorf(u1 * Nl);
    int g2 = (int)floorf(u2 * Nl);

    float vmin0 = (float)g0 * box + mn;
    float vmin1 = (float)g1 * box + mn;
    float vmin2 = (float)g2 * box + mn;

    float den0 = (vmin0 + box) - vmin0;
    float den1 = (vmin1 + box) - vmin1;
    float den2 = (vmin2 + box) - vmin2;

    float wx = (x0 - vmin0) / den0;
    float wy = (x1 - vmin1) / den1;
    float wz = (x2 - vmin2) / den2;

    unsigned hx0 = (unsigned)g0;
    unsigned hx1 = (unsigned)(g0 + 1);
    unsigned hy0 = (unsigned)g1       * 2654435761u;
    unsigned hy1 = (unsigned)(g1 + 1) * 2654435761u;
    unsigned hz0 = (unsigned)g2       * 805459861u;
    unsigned hz1 = (unsigned)(g2 + 1) * 805459861u;

    float2 e000 = tab[(hx0 ^ hy0 ^ hz0) & HMASK];
    float2 e001 = tab[(hx0 ^ hy0 ^ hz1) & HMASK];
    float2 e010 = tab[(hx0 ^ hy1 ^ hz0) & HMASK];
    float2 e011 = tab[(hx0 ^ hy1 ^ hz1) & HMASK];
    float2 e100 = tab[(hx1 ^ hy0 ^ hz0) & HMASK];
    float2 e101 = tab[(hx1 ^ hy0 ^ hz1) & HMASK];
    float2 e110 = tab[(hx1 ^ hy1 ^ hz0) & HMASK];
    float2 e111 = tab[(hx1 ^ hy1 ^ hz1) & HMASK];

    float omx = 1.0f - wx, omy = 1.0f - wy, omz = 1.0f - wz;
    {
        float c00 = e000.x * omx + e100.x * wx;
        float c01 = e001.x * omx + e101.x * wx;
        float c10 = e010.x * omx + e110.x * wx;
        float c11 = e011.x * omx + e111.x * wx;
        float c0  = c00 * omy + c10 * wy;
        float c1  = c01 * omy + c11 * wy;
        *r0 = c0 * omz + c1 * wz;
    }
    {
        float c00 = e000.y * omx + e100.y * wx;
        float c01 = e001.y * omx + e101.y * wx;
        float c10 = e010.y * omx + e110.y * wx;
        float c11 = e011.y * omx + e111.y * wx;
        float c0  = c00 * omy + c10 * wy;
        float c1  = c01 * omy + c11 * wy;
        *r1 = c0 * omz + c1 * wz;
    }
}

// ---------- fine-level body ----------

template<int L, bool DO_HIST, bool DO_MASK>
__device__ __forceinline__ void fine_body(
    const float* __restrict__ xin, const float* __restrict__ tables,
    float* __restrict__ out, unsigned* __restrict__ hist, int p)
{
#pragma clang fp contract(off)
    float x0 = xin[3 * p], x1 = xin[3 * p + 1], x2 = xin[3 * p + 2];
    float u0, u1, u2; uvw(x0, x1, x2, &u0, &u1, &u2);

    if (DO_HIST)
        atomicAdd(&hist[morton_key(u0, u1, u2)], 1u);

    const float2* tab = (const float2*)tables + (size_t)L * TSIZE;
    float r0, r1;
    level_lerp(x0, x1, x2, u0, u1, u2, NLF_TAB[L], tab, &r0, &r1);
    *(float2*)(out + (size_t)p * 32 + 2 * L) = make_float2(r0, r1);

    if (DO_MASK) {
        const float mn = -1.5f, mx = 1.5f;
        float keep = (x0 >= mn && x0 <= mx &&
                      x1 >= mn && x1 <= mx &&
                      x2 >= mn && x2 <= mx) ? 1.0f : 0.0f;
        out[(size_t)NPTS * 32 + p] = keep;
    }
}

template<int L, bool DO_HIST, bool DO_MASK>
__global__ __launch_bounds__(256)
void fine_kernel(const float* __restrict__ xin,
                 const float* __restrict__ tables,
                 float* __restrict__ out,
                 unsigned* __restrict__ hist)
{
    int p = blockIdx.x * 256 + threadIdx.x;
    if (p >= NPTS) return;
    fine_body<L, DO_HIST, DO_MASK>(xin, tables, out, hist, p);
}

// fine14 + scan: blocks 0..4095 do L14; block 4096 scans the (complete)
// histogram into cursors in-place. One tiny block - no working-set impact.
__global__ __launch_bounds__(256)
void fine14_scan(const float* __restrict__ xin,
                 const float* __restrict__ tables,
                 float* __restrict__ out,
                 unsigned* __restrict__ hist)
{
    __shared__ unsigned part[256];
    if (blockIdx.x < 4096) {
        int p = blockIdx.x * 256 + threadIdx.x;
        fine_body<14, false, false>(xin, tables, out, hist, p);
        return;
    }
    // --- scan block: 256 threads x 128 bins ---
    int t = threadIdx.x;
    unsigned s = 0;
    for (int i = 0; i < 128; ++i) s += hist[t * 128 + i];
    part[t] = s;
    __syncthreads();
    for (int off = 1; off < 256; off <<= 1) {
        unsigned v = (t >= off) ? part[t - off] : 0;
        __syncthreads();
        part[t] += v;
        __syncthreads();
    }
    unsigned base = (t == 0) ? 0u : part[t - 1];
    for (int i = 0; i < 128; ++i) {
        unsigned c = hist[t * 128 + i];
        hist[t * 128 + i] = base;     // cursor
        base += c;
    }
}

// ---------- sort kernels ----------

__global__ __launch_bounds__(256)
void scatter_kernel(const float* __restrict__ xin,
                    unsigned* __restrict__ cursor,
                    unsigned* __restrict__ sidx,
                    float4* __restrict__ sx4)
{
    int p = blockIdx.x * 256 + threadIdx.x;
    if (p >= NPTS) return;
    float x0 = xin[3 * p], x1 = xin[3 * p + 1], x2 = xin[3 * p + 2];
    float u0, u1, u2; uvw(x0, x1, x2, &u0, &u1, &u2);
    unsigned pos = atomicAdd(&cursor[morton_key(u0, u1, u2)], 1u);
    sidx[pos] = (unsigned)p;
    sx4[pos] = make_float4(x0, x1, x2, 0.0f);
}

// ---------- sorted compute kernels ----------

// Levels 0..7 over sorted points; writes first 64B of each row (full line).
__global__ __launch_bounds__(256)
void coarse_sorted(const unsigned* __restrict__ sidx,
                   const float4* __restrict__ sx4,
                   const float* __restrict__ tables,
                   float* __restrict__ out)
{
#pragma clang fp contract(off)
    int s = blockIdx.x * 256 + threadIdx.x;
    if (s >= NPTS) return;
    unsigned p = sidx[s];
    float4 xv = sx4[s];
    float u0, u1, u2; uvw(xv.x, xv.y, xv.z, &u0, &u1, &u2);

    float res[16];
#pragma unroll
    for (int l = 0; l < 8; ++l) {
        const float2* tab = (const float2*)tables + (size_t)l * TSIZE;
        level_lerp(xv.x, xv.y, xv.z, u0, u1, u2, NLF_TAB[l], tab,
                   &res[2 * l], &res[2 * l + 1]);
    }

    float4* orow = (float4*)(out + (size_t)p * 32);
#pragma unroll
    for (int i = 0; i < 4; ++i)
        orow[i] = make_float4(res[4 * i + 0], res[4 * i + 1],
                              res[4 * i + 2], res[4 * i + 3]);
}

// Levels 8,9 over sorted points; writes one float4 (floats 16..19).
__global__ __launch_bounds__(256)
void mid_sorted(const unsigned* __restrict__ sidx,
                const float4* __restrict__ sx4,
                const float* __restrict__ tables,
                float* __restrict__ out)
{
#pragma clang fp contract(off)
    int s = blockIdx.x * 256 + threadIdx.x;
    if (s >= NPTS) return;
    unsigned p = sidx[s];
    float4 xv = sx4[s];
    float u0, u1, u2; uvw(xv.x, xv.y, xv.z, &u0, &u1, &u2);

    float r[4];
    {
        const float2* tab = (const float2*)tables + (size_t)8 * TSIZE;
        level_lerp(xv.x, xv.y, xv.z, u0, u1, u2, NLF_TAB[8], tab, &r[0], &r[1]);
    }
    {
        const float2* tab = (const float2*)tables + (size_t)9 * TSIZE;
        level_lerp(xv.x, xv.y, xv.z, u0, u1, u2, NLF_TAB[9], tab, &r[2], &r[3]);
    }
    *(float4*)(out + (size_t)p * 32 + 16) = make_float4(r[0], r[1], r[2], r[3]);
}

// ---------- fallback (no-workspace path) ----------

__global__ __launch_bounds__(256)
void coarse_kernel(const float* __restrict__ xin,
                   const float* __restrict__ tables,
                   float* __restrict__ out)
{
#pragma clang fp contract(off)
    int p = blockIdx.x * 256 + threadIdx.x;
    if (p >= NPTS) return;
    float x0 = xin[3 * p], x1 = xin[3 * p + 1], x2 = xin[3 * p + 2];
    float u0, u1, u2; uvw(x0, x1, x2, &u0, &u1, &u2);

    float res[16];
#pragma unroll
    for (int l = 0; l < 8; ++l) {
        const float2* tab = (const float2*)tables + (size_t)l * TSIZE;
        level_lerp(x0, x1, x2, u0, u1, u2, NLF_TAB[l], tab,
                   &res[2 * l], &res[2 * l + 1]);
    }
    float4* orow = (float4*)(out + (size_t)p * 32);
#pragma unroll
    for (int i = 0; i < 4; ++i)
        orow[i] = make_float4(res[4 * i + 0], res[4 * i + 1],
                              res[4 * i + 2], res[4 * i + 3]);
}

extern "C" void kernel_launch(void* const* d_in, const int* in_sizes, int n_in,
                              void* d_out, int out_size, void* d_ws, size_t ws_size,
                              hipStream_t stream) {
    const float* x      = (const float*)d_in[0];
    const float* tables = (const float*)d_in[2];
    float* out = (float*)d_out;

    int n = in_sizes[0] / 3;           // 1048576
    int blocks = (n + 255) / 256;      // 4096

    const size_t HIST_B   = (size_t)NBUCK * 4;              // 128 KB
    const size_t SIDX_OFF = 131072;                         // aligned
    const size_t SX4_OFF  = SIDX_OFF + (size_t)NPTS * 4;    // +4 MB
    const size_t NEEDED   = SX4_OFF + (size_t)NPTS * 16;    // ≈ 20.2 MB

    if (ws_size >= NEEDED) {
        unsigned* hist = (unsigned*)d_ws;
        unsigned* sidx = (unsigned*)((char*)d_ws + SIDX_OFF);
        float4*   sx4  = (float4*)((char*)d_ws + SX4_OFF);

        hipMemsetAsync(hist, 0, HIST_B, stream);

        // One table L2-resident per launch; hist/scan ride along for free.
        fine_kernel<15, true , false><<<blocks, 256, 0, stream>>>(x, tables, out, hist);
        fine14_scan<<<blocks + 1, 256, 0, stream>>>(x, tables, out, hist);
        fine_kernel<13, false, false><<<blocks, 256, 0, stream>>>(x, tables, out, hist);
        fine_kernel<12, false, false><<<blocks, 256, 0, stream>>>(x, tables, out, hist);
        fine_kernel<11, false, false><<<blocks, 256, 0, stream>>>(x, tables, out, hist);
        fine_kernel<10, false, true ><<<blocks, 256, 0, stream>>>(x, tables, out, hist);

        scatter_kernel<<<blocks, 256, 0, stream>>>(x, hist, sidx, sx4);
        coarse_sorted<<<blocks, 256, 0, stream>>>(sidx, sx4, tables, out);
        mid_sorted<<<blocks, 256, 0, stream>>>(sidx, sx4, tables, out);
    } else {
        coarse_kernel<<<blocks, 256, 0, stream>>>(x, tables, out);
        fine_kernel< 8, false, false><<<blocks, 256, 0, stream>>>(x, tables, out, nullptr);
        fine_kernel< 9, false, false><<<blocks, 256, 0, stream>>>(x, tables, out, nullptr);
        fine_kernel<10, false, true ><<<blocks, 256, 0, stream>>>(x, tables, out, nullptr);
        fine_kernel<11, false, false><<<blocks, 256, 0, stream>>>(x, tables, out, nullptr);
        fine_kernel<12, false, false><<<blocks, 256, 0, stream>>>(x, tables, out, nullptr);
        fine_kernel<13, false, false><<<blocks, 256, 0, stream>>>(x, tables, out, nullptr);
        fine_kernel<14, false, false><<<blocks, 256, 0, stream>>>(x, tables, out, nullptr);
        fine_kernel<15, false, false><<<blocks, 256, 0, stream>>>(x, tables, out, nullptr);
    }
}